// Round 5
// baseline (99.480 us; speedup 1.0000x reference)
//
#include <hip/hip_runtime.h>

// out[b,c,h,w] = (c % 2 == 0) ? relu(x) : x ; x: (16,64,256,256) f32 contiguous.
// Memory-bound streaming op. float4, unroll-8, block-contiguous tiling:
// block b owns float4 range [b*2048, (b+1)*2048) = 32 KiB contiguous.
// Thread t handles b*2048 + k*256 + t, k=0..7 (coalesced per wave, 8-deep
// vmcnt queue, all accesses within one 32 KiB region).
//
// Channel period = 16384 float4s; 2048 | 16384, so each block is entirely
// inside one channel: mask = ((b >> 3) & 1) == 0 (even channel -> relu).
// Branch is block-uniform => zero divergence.

typedef float f32x4 __attribute__((ext_vector_type(4)));

__device__ __forceinline__ f32x4 relu4(f32x4 v) {
    v.x = fmaxf(v.x, 0.0f);
    v.y = fmaxf(v.y, 0.0f);
    v.z = fmaxf(v.z, 0.0f);
    v.w = fmaxf(v.w, 0.0f);
    return v;
}

__global__ __launch_bounds__(256) void Grid2DPartialPositiver_kernel(
    const f32x4* __restrict__ in, f32x4* __restrict__ out, unsigned int n4) {
    const unsigned int b = blockIdx.x;
    const unsigned int base = b * 2048u + threadIdx.x;
    const bool pos = ((b >> 3) & 1u) == 0u;  // even channel -> relu

    if (base + 7u * 256u < n4) {
        f32x4 v[8];
#pragma unroll
        for (int k = 0; k < 8; ++k)
            v[k] = __builtin_nontemporal_load(&in[base + (unsigned)k * 256u]);
        if (pos) {
#pragma unroll
            for (int k = 0; k < 8; ++k) v[k] = relu4(v[k]);
        }
#pragma unroll
        for (int k = 0; k < 8; ++k)
            __builtin_nontemporal_store(v[k], &out[base + (unsigned)k * 256u]);
    } else {
        for (unsigned int i = base; i < n4; i += 256u) {
            f32x4 v = __builtin_nontemporal_load(&in[i]);
            if (((i >> 14) & 1u) == 0u) v = relu4(v);
            __builtin_nontemporal_store(v, &out[i]);
        }
    }
}

extern "C" void kernel_launch(void* const* d_in, const int* in_sizes, int n_in,
                              void* d_out, int out_size, void* d_ws, size_t ws_size,
                              hipStream_t stream) {
    const f32x4* x = (const f32x4*)d_in[0];
    f32x4* out = (f32x4*)d_out;
    const unsigned int n4 = (unsigned int)(out_size / 4);  // 16,777,216
    const int block = 256;
    // one contiguous 2048-float4 (32 KiB) tile per block: 8192 blocks
    const int grid = (int)((n4 + 2047u) / 2048u);
    Grid2DPartialPositiver_kernel<<<grid, block, 0, stream>>>(x, out, n4);
}

// Round 6
// 82.026 us; speedup vs baseline: 1.2128x; 1.2128x over previous
//
#include <hip/hip_runtime.h>

// out[b,c,h,w] = (c % 2 == 0) ? relu(x) : x ; x: (16,64,256,256) f32 contiguous.
// Memory-bound streaming op. float4, unroll-4, block-contiguous 16 KiB tiles
// (round-4 structure, best so far: 93.2 us = 5.76 TB/s).
// This round: nt loads kept (read-once), nt REMOVED from stores — let L2
// write-combine/buffer the streaming output (fill kernels with cached stores
// sustain ~7 TB/s write-only on this chip).
//
// Channel period = 16384 float4s; 1024 | 16384 => block entirely within one
// channel; mask = ((b >> 4) & 1) == 0 (block-uniform, zero divergence).

typedef float f32x4 __attribute__((ext_vector_type(4)));

__device__ __forceinline__ f32x4 relu4(f32x4 v) {
    v.x = fmaxf(v.x, 0.0f);
    v.y = fmaxf(v.y, 0.0f);
    v.z = fmaxf(v.z, 0.0f);
    v.w = fmaxf(v.w, 0.0f);
    return v;
}

__global__ __launch_bounds__(256) void Grid2DPartialPositiver_kernel(
    const f32x4* __restrict__ in, f32x4* __restrict__ out, unsigned int n4) {
    const unsigned int b = blockIdx.x;
    const unsigned int base = b * 1024u + threadIdx.x;
    const bool pos = ((b >> 4) & 1u) == 0u;  // even channel -> relu

    const unsigned int i0 = base;
    const unsigned int i1 = base + 256u;
    const unsigned int i2 = base + 512u;
    const unsigned int i3 = base + 768u;

    if (i3 < n4) {
        f32x4 v0 = __builtin_nontemporal_load(&in[i0]);
        f32x4 v1 = __builtin_nontemporal_load(&in[i1]);
        f32x4 v2 = __builtin_nontemporal_load(&in[i2]);
        f32x4 v3 = __builtin_nontemporal_load(&in[i3]);
        if (pos) {
            v0 = relu4(v0);
            v1 = relu4(v1);
            v2 = relu4(v2);
            v3 = relu4(v3);
        }
        out[i0] = v0;
        out[i1] = v1;
        out[i2] = v2;
        out[i3] = v3;
    } else {
        for (unsigned int i = i0; i < n4; i += 256u) {
            f32x4 v = __builtin_nontemporal_load(&in[i]);
            if (((i >> 14) & 1u) == 0u) v = relu4(v);
            out[i] = v;
        }
    }
}

extern "C" void kernel_launch(void* const* d_in, const int* in_sizes, int n_in,
                              void* d_out, int out_size, void* d_ws, size_t ws_size,
                              hipStream_t stream) {
    const f32x4* x = (const f32x4*)d_in[0];
    f32x4* out = (f32x4*)d_out;
    const unsigned int n4 = (unsigned int)(out_size / 4);  // 16,777,216
    const int block = 256;
    // one contiguous 1024-float4 (16 KiB) tile per block: 16384 blocks
    const int grid = (int)((n4 + 1023u) / 1024u);
    Grid2DPartialPositiver_kernel<<<grid, block, 0, stream>>>(x, out, n4);
}